// Round 3
// baseline (291.675 us; speedup 1.0000x reference)
//
#include <hip/hip_runtime.h>
#include <hip/hip_bf16.h>

typedef unsigned short ushort_t;
typedef short bf16x8 __attribute__((ext_vector_type(8)));
typedef float f32x4 __attribute__((ext_vector_type(4)));

#define B_ 8
#define N_ 128
#define E_ 16256           // 128*127
#define BE 130048          // 8*E_

#define VM_WAIT(n) asm volatile("s_waitcnt vmcnt(" #n ")" ::: "memory")

__device__ __forceinline__ float eluf(float x) {
    return x > 0.0f ? x : __expf(x) - 1.0f;
}
__device__ __forceinline__ ushort_t f2bf(float f) {
    union { float f; unsigned u; } v; v.f = f;
    return (ushort_t)((v.u + 0x7fffu + ((v.u >> 16) & 1u)) >> 16);
}
__device__ __forceinline__ float bf2f(ushort_t h) {
    union { unsigned u; float f; } v; v.u = ((unsigned)h) << 16;
    return v.f;
}

// async global->LDS, 16B per lane; LDS dest = wave-uniform base + lane*16.
__device__ __forceinline__ void glds16(void* lds, const void* g) {
    __builtin_amdgcn_global_load_lds(
        (const __attribute__((address_space(1))) unsigned int*)g,
        (__attribute__((address_space(3))) unsigned int*)lds, 16, 0, 0);
}

// ---------------- weight image builders (fused) ----------------
// img64: chunk c (64k x 256n = 32KB): img[c][n][u'][j] = w[c*64 + (u'^(n&7))*8 + j][n]
__device__ __forceinline__ void img64_elem(const float* __restrict__ w,
                                           ushort_t* __restrict__ img, int i) {
    int c = i >> 14;  int r = i & 16383;
    int n = r >> 6;   int wdx = r & 63;
    int up = wdx >> 3, j = wdx & 7;
    int u = up ^ (n & 7);
    int k = c * 64 + u * 8 + j;
    img[i] = f2bf(w[(size_t)k * 256 + n]);
}
// img32: chunk c (32k x 256n = 16KB): img[c][n][q'][j] = w[c*32 + (q'^((n>>1)&3))*8 + j][n]
__device__ __forceinline__ void img32_elem(const float* __restrict__ w,
                                           ushort_t* __restrict__ img, int i) {
    int c = i >> 13;  int r = i & 8191;
    int n = r >> 5;   int jq = r & 31;
    int quad = jq >> 3, j = jq & 7;
    int kc = quad ^ ((n >> 1) & 3);
    int k = c * 32 + kc * 8 + j;
    img[i] = f2bf(w[(size_t)k * 256 + n]);
}

__global__ __launch_bounds__(256) void wprep_all(
    const float* __restrict__ w1e1, ushort_t* __restrict__ i1,
    const float* __restrict__ w2e1, ushort_t* __restrict__ i2,
    const float* __restrict__ w1e2, ushort_t* __restrict__ i3,
    const float* __restrict__ w2e2, ushort_t* __restrict__ i4)
{
    int gid = blockIdx.x * 256 + threadIdx.x;
    if (gid < 131072)            img64_elem(w1e1, i1, gid);
    else if (gid < 196608)       img32_elem(w2e1, i2, gid - 131072);
    else if (gid < 393216)       img64_elem(w1e2, i3, gid - 196608);
    else                         img32_elem(w2e2, i4, gid - 393216);
}

// ---------------- node MLP: fp32, 4 rows per block ----------------
template<int K>
__global__ __launch_bounds__(256) void node_mlp4(
    const float* __restrict__ in, const float* __restrict__ w1,
    const float* __restrict__ b1, const float* __restrict__ w2,
    const float* __restrict__ b2, ushort_t* __restrict__ outbf)
{
    __shared__ float xl[4][K];
    __shared__ float hl[4][256];
    const int r0 = blockIdx.x * 4, t = threadIdx.x;
    for (int idx = t; idx < 4 * K; idx += 256) {
        int r = idx / K, k = idx - r * K;
        xl[r][k] = in[(size_t)(r0 + r) * K + k];
    }
    __syncthreads();
    float a[4];
    const float bb1 = b1[t];
    #pragma unroll
    for (int r = 0; r < 4; ++r) a[r] = bb1;
    #pragma unroll 4
    for (int k = 0; k < K; ++k) {
        const float wv = w1[(size_t)k * 256 + t];
        #pragma unroll
        for (int r = 0; r < 4; ++r) a[r] = fmaf(xl[r][k], wv, a[r]);
    }
    #pragma unroll
    for (int r = 0; r < 4; ++r) hl[r][t] = eluf(a[r]);
    __syncthreads();
    const float bb2 = b2[t];
    #pragma unroll
    for (int r = 0; r < 4; ++r) a[r] = bb2;
    #pragma unroll 4
    for (int k = 0; k < 256; ++k) {
        const float wv = w2[(size_t)k * 256 + t];
        #pragma unroll
        for (int r = 0; r < 4; ++r) a[r] = fmaf(hl[r][k], wv, a[r]);
    }
    #pragma unroll
    for (int r = 0; r < 4; ++r)
        outbf[(size_t)(r0 + r) * 256 + t] = f2bf(eluf(a[r]));
}

// ---------------- contiguous segment-sum aggregation ----------------
__global__ __launch_bounds__(256) void agg_kernel(const ushort_t* __restrict__ e1,
                                                  float* __restrict__ agg)
{
    __shared__ float red[8][256];
    const int bn = blockIdx.x;
    const int b = bn >> 7, n = bn & 127;
    const int t = threadIdx.x;
    const int u = t & 31, g = t >> 5;
    const ushort_t* base = e1 + ((size_t)b * E_ + (size_t)n * 127) * 256 + u * 8;
    float s[8] = {0.f,0.f,0.f,0.f,0.f,0.f,0.f,0.f};
    for (int j = g; j < 127; j += 8) {
        bf16x8 v = *(const bf16x8*)(base + (size_t)j * 256);
        #pragma unroll
        for (int c = 0; c < 8; ++c) s[c] += bf2f((ushort_t)v[c]);
    }
    #pragma unroll
    for (int c = 0; c < 8; ++c) red[g][u * 8 + c] = s[c];
    __syncthreads();
    float tot = 0.f;
    #pragma unroll
    for (int gg = 0; gg < 8; ++gg) tot += red[gg][t];
    agg[(size_t)bn * 256 + t] = tot;
}

// ---------------- fused 2-layer edge MLP, counted-vmcnt pipeline ----------------
// LDS layout (160KB dynamic):
//   layer 1: A ring [p*32K, +32K)  B ring [64K + p*32K, +32K)   (inside future Hid)
//   layer 2: Hid [0,128K) (256 rows x 512B, XOR-swizzled)  B2 ring [128K + p*16K, +16K)
template<int K1, int NSEG, bool FINAL>
__global__ __launch_bounds__(512, 2) void edge_gemm(
    const ushort_t* __restrict__ hnode,     // [B*N][256] bf16
    const ushort_t* __restrict__ skipsrc,   // [BE][256] bf16 (NSEG==3)
    const ushort_t* __restrict__ w1img, const float* __restrict__ b1,
    const ushort_t* __restrict__ w2img, const float* __restrict__ b2,
    ushort_t* __restrict__ eout,
    const float* __restrict__ ow, const float* __restrict__ ob,
    float* __restrict__ out)
{
    extern __shared__ char smem[];

    const int t    = threadIdx.x;
    const int wid  = t >> 6;
    const int lane = t & 63;
    const int lr   = lane & 15;
    const int lg   = lane >> 4;
    const int wr   = wid >> 1;    // 0..3 (64-row group)
    const int wc   = wid & 1;     // 0..1 (128-col group)
    const int q4   = (lg ^ ((lr >> 1) & 3)) << 4;   // layer-2 B swizzle

    const int blockRow = blockIdx.x * 256;

    // ---- per-lane A-staging row pointers: 4 rows (it=0..3), swizzled unit offset ----
    const int uoff = ((lane & 7) ^ ((lane >> 3) & 7)) * 8;
    const ushort_t* a0[4];
    const ushort_t* a1[4];
    const ushort_t* a2[4];
    #pragma unroll
    for (int it = 0; it < 4; ++it) {
        int r  = wid * 32 + it * 8 + (lane >> 3);
        int rg = blockRow + r;
        int b  = rg / E_;  int e = rg - b * E_;
        int rcv = e / 127; int kk = e - rcv * 127;
        int snd = kk + (kk >= rcv ? 1 : 0);
        a0[it] = hnode + (size_t)(b * N_ + rcv) * 256 + uoff;
        a1[it] = hnode + (size_t)(b * N_ + snd) * 256 + uoff;
        a2[it] = (NSEG == 3) ? skipsrc + (size_t)rg * 256 + uoff : a0[it];
    }

    float bias1[8], bias2[8];
    #pragma unroll
    for (int f = 0; f < 8; ++f) {
        int col = wc * 128 + f * 16 + lr;
        bias1[f] = b1[col];
        bias2[f] = b2[col];
    }

    f32x4 acc[4][8];
    #pragma unroll
    for (int m = 0; m < 4; ++m)
        #pragma unroll
        for (int f = 0; f < 8; ++f) acc[m][f] = f32x4{0.f, 0.f, 0.f, 0.f};

    // ---- staging helpers (counts per wave: B64=4, A64=4, B32=2 glds) ----
    auto stageB64 = [&](int c, int p) {
        const char* src = (const char*)w1img + (size_t)c * 32768 + wid * 4096 + lane * 16;
        char* dst = smem + 65536 + p * 32768 + wid * 4096;
        #pragma unroll
        for (int it = 0; it < 4; ++it) glds16(dst + it * 1024, src + it * 1024);
    };
    auto stageA64 = [&](int k0, int p) {
        char* dst = smem + p * 32768 + wid * 4096;
        #pragma unroll
        for (int it = 0; it < 4; ++it) {
            const ushort_t* bp;
            if (NSEG == 3) bp = (k0 < 256) ? a0[it] : (k0 < 512 ? a1[it] : a2[it]);
            else           bp = (k0 < 256) ? a0[it] : a1[it];
            glds16(dst + it * 1024, bp + (k0 & 255));
        }
    };
    auto stageB2 = [&](int c, int p) {
        const char* src = (const char*)w2img + (size_t)c * 16384 + wid * 2048 + lane * 16;
        char* dst = smem + 131072 + p * 16384 + wid * 2048;
        glds16(dst, src);
        glds16(dst + 1024, src + 1024);
    };

    // ================= layer 1: K-chunk 64, ring 2, counted vmcnt =================
    constexpr int NC1 = K1 / 64;
    stageB64(0, 0);
    stageA64(0, 0);                       // 8 ops in flight
    #pragma unroll 2
    for (int c = 0; c < NC1; ++c) {
        const int p = c & 1;
        if (c + 1 < NC1) {
            stageB64(c + 1, p ^ 1);
            stageA64((c + 1) * 64, p ^ 1);
            VM_WAIT(8);                   // chunk c landed; chunk c+1 stays in flight
        } else {
            stageB2(0, 0);                // prefetch layer-2 B chunk 0
            VM_WAIT(2);
        }
        __builtin_amdgcn_s_barrier();     // b_start: all waves' chunk-c stage visible
        const char* Ab = smem + p * 32768;
        const char* Bb = smem + 65536 + p * 32768;
        #pragma unroll
        for (int ks = 0; ks < 2; ++ks) {
            bf16x8 a[4], b[8];
            const int sw = (ks * 4 + lg);
            #pragma unroll
            for (int m = 0; m < 4; ++m)
                a[m] = *(const bf16x8*)(Ab + (wr * 64 + m * 16 + lr) * 128 + ((sw ^ (lr & 7)) << 4));
            #pragma unroll
            for (int f = 0; f < 8; ++f)
                b[f] = *(const bf16x8*)(Bb + (wc * 128 + f * 16 + lr) * 128 + ((sw ^ (lr & 7)) << 4));
            __builtin_amdgcn_s_setprio(1);
            #pragma unroll
            for (int m = 0; m < 4; ++m)
                #pragma unroll
                for (int f = 0; f < 8; ++f)
                    acc[m][f] = __builtin_amdgcn_mfma_f32_16x16x32_bf16(a[m], b[f], acc[m][f], 0, 0, 0);
            __builtin_amdgcn_s_setprio(0);
        }
        asm volatile("" ::: "memory");
        __builtin_amdgcn_s_barrier();     // b_end: all reads of ring p done
    }

    // ---- transition: bias+elu -> Hid (bf16, XOR layout), reset acc ----
    #pragma unroll
    for (int m = 0; m < 4; ++m)
        #pragma unroll
        for (int f = 0; f < 8; ++f) {
            const int col = wc * 128 + f * 16 + lr;
            const int ch = col >> 3;
            #pragma unroll
            for (int r = 0; r < 4; ++r) {
                const int row = wr * 64 + m * 16 + lg * 4 + r;
                float v = eluf(acc[m][f][r] + bias1[f]);
                *(ushort_t*)(smem + row * 512 + ((ch ^ (row & 7)) << 4) + ((col & 7) << 1)) = f2bf(v);
            }
            acc[m][f] = f32x4{0.f, 0.f, 0.f, 0.f};
        }
    asm volatile("s_waitcnt lgkmcnt(0)" ::: "memory");   // Hid writes drained (pre-barrier)

    // ================= layer 2: K-chunk 32, B2 ring 2, counted vmcnt =================
    #pragma unroll 2
    for (int c = 0; c < 8; ++c) {
        const int p = c & 1;
        if (c < 7) { stageB2(c + 1, p ^ 1); VM_WAIT(2); }
        else       { VM_WAIT(0); }
        __builtin_amdgcn_s_barrier();     // b_start (c==0: also publishes Hid)
        const char* B2p = smem + 131072 + p * 16384;
        bf16x8 a[4], b[8];
        const int qh = ((c * 4 + lg) ^ (lr & 7)) << 4;
        #pragma unroll
        for (int m = 0; m < 4; ++m)
            a[m] = *(const bf16x8*)(smem + (wr * 64 + m * 16 + lr) * 512 + qh);
        #pragma unroll
        for (int f = 0; f < 8; ++f)
            b[f] = *(const bf16x8*)(B2p + (wc * 128 + f * 16 + lr) * 64 + q4);
        __builtin_amdgcn_s_setprio(1);
        #pragma unroll
        for (int m = 0; m < 4; ++m)
            #pragma unroll
            for (int f = 0; f < 8; ++f)
                acc[m][f] = __builtin_amdgcn_mfma_f32_16x16x32_bf16(a[m], b[f], acc[m][f], 0, 0, 0);
        __builtin_amdgcn_s_setprio(0);
        asm volatile("" ::: "memory");
        __builtin_amdgcn_s_barrier();     // b_end
    }

    if (!FINAL) {
        // ---- epilogue: elu+bias -> wave-private LDS slice -> coalesced stores ----
        char* slice = smem + wid * 16384;
        #pragma unroll
        for (int m = 0; m < 4; ++m)
            #pragma unroll
            for (int f = 0; f < 8; ++f) {
                const int col = f * 16 + lr;         // local 0..127
                const int cc = col >> 3;
                #pragma unroll
                for (int r = 0; r < 4; ++r) {
                    const int row = m * 16 + lg * 4 + r;   // local 0..63
                    float v = eluf(acc[m][f][r] + bias2[f]);
                    *(ushort_t*)(slice + row * 256 + ((cc ^ (row & 7)) << 4) + ((col & 7) << 1)) = f2bf(v);
                }
            }
        asm volatile("s_waitcnt lgkmcnt(0)" ::: "memory");
        #pragma unroll
        for (int it = 0; it < 16; ++it) {
            const int q = it * 64 + lane;
            const int row = q >> 4, ccp = q & 15;
            bf16x8 v = *(const bf16x8*)(slice + row * 256 + (ccp << 4));
            const int cc = ccp ^ (row & 7);
            const int grow = blockRow + wr * 64 + row;
            *(bf16x8*)(eout + (size_t)grow * 256 + wc * 128 + cc * 8) = v;
        }
    } else {
        // ---- epilogue: fused projection to [row][2] ----
        float ow0[8], ow1[8];
        #pragma unroll
        for (int f = 0; f < 8; ++f) {
            int col = wc * 128 + f * 16 + lr;
            ow0[f] = ow[col * 2 + 0];
            ow1[f] = ow[col * 2 + 1];
        }
        float s0[4][4], s1[4][4];
        #pragma unroll
        for (int m = 0; m < 4; ++m)
            #pragma unroll
            for (int r = 0; r < 4; ++r) { s0[m][r] = 0.f; s1[m][r] = 0.f; }
        #pragma unroll
        for (int m = 0; m < 4; ++m)
            #pragma unroll
            for (int f = 0; f < 8; ++f)
                #pragma unroll
                for (int r = 0; r < 4; ++r) {
                    float v = eluf(acc[m][f][r] + bias2[f]);
                    s0[m][r] = fmaf(v, ow0[f], s0[m][r]);
                    s1[m][r] = fmaf(v, ow1[f], s1[m][r]);
                }
        #pragma unroll
        for (int msk = 1; msk <= 8; msk <<= 1)
            #pragma unroll
            for (int m = 0; m < 4; ++m)
                #pragma unroll
                for (int r = 0; r < 4; ++r) {
                    s0[m][r] += __shfl_xor(s0[m][r], msk);
                    s1[m][r] += __shfl_xor(s1[m][r], msk);
                }
        float* part = (float*)smem;   // 4KB, Hid region free now
        if (lr == 0) {
            #pragma unroll
            for (int m = 0; m < 4; ++m)
                #pragma unroll
                for (int r = 0; r < 4; ++r) {
                    const int row = wr * 64 + m * 16 + lg * 4 + r;
                    part[(row * 2 + 0) * 2 + wc] = s0[m][r];
                    part[(row * 2 + 1) * 2 + wc] = s1[m][r];
                }
        }
        __syncthreads();
        const int row = t >> 1, chn = t & 1;
        float val = part[(row * 2 + chn) * 2 + 0] + part[(row * 2 + chn) * 2 + 1] + ob[chn];
        out[(size_t)(blockRow + row) * 2 + chn] = val;
    }
}

extern "C" void kernel_launch(void* const* d_in, const int* in_sizes, int n_in,
                              void* d_out, int out_size, void* d_ws, size_t ws_size,
                              hipStream_t stream)
{
    const float* x    = (const float*)d_in[0];
    const float* n1w1 = (const float*)d_in[3];
    const float* n1b1 = (const float*)d_in[4];
    const float* n1w2 = (const float*)d_in[5];
    const float* n1b2 = (const float*)d_in[6];
    const float* e1w1 = (const float*)d_in[7];
    const float* e1b1 = (const float*)d_in[8];
    const float* e1w2 = (const float*)d_in[9];
    const float* e1b2 = (const float*)d_in[10];
    const float* n2w1 = (const float*)d_in[11];
    const float* n2b1 = (const float*)d_in[12];
    const float* n2w2 = (const float*)d_in[13];
    const float* n2b2 = (const float*)d_in[14];
    const float* e2w1 = (const float*)d_in[15];
    const float* e2b1 = (const float*)d_in[16];
    const float* e2w2 = (const float*)d_in[17];
    const float* e2b2 = (const float*)d_in[18];
    const float* ow   = (const float*)d_in[19];
    const float* ob   = (const float*)d_in[20];

    char* ws = (char*)d_ws;
    ushort_t* h1   = (ushort_t*)(ws + 0);                      // 512 KB
    ushort_t* h2   = (ushort_t*)(ws + (512u << 10));           // 512 KB
    float*    aggf = (float*)(ws + (1u << 20));                // 1 MB
    ushort_t* e1   = (ushort_t*)(ws + (2u << 20));             // 66.6 MB
    size_t off = (size_t)(2u << 20) + (size_t)BE * 256 * 2;
    ushort_t* w1e1 = (ushort_t*)(ws + off); off += (size_t)512 * 256 * 2;
    ushort_t* w2e1 = (ushort_t*)(ws + off); off += (size_t)256 * 256 * 2;
    ushort_t* w1e2 = (ushort_t*)(ws + off); off += (size_t)768 * 256 * 2;
    ushort_t* w2e2 = (ushort_t*)(ws + off);

    float* out = (float*)d_out;

    hipFuncSetAttribute((const void*)edge_gemm<512, 2, false>,
                        hipFuncAttributeMaxDynamicSharedMemorySize, 163840);
    hipFuncSetAttribute((const void*)edge_gemm<768, 3, true>,
                        hipFuncAttributeMaxDynamicSharedMemorySize, 163840);

    wprep_all<<<1792, 256, 0, stream>>>(e1w1, w1e1, e1w2, w2e1, e2w1, w1e2, e2w2, w2e2);

    node_mlp4<196><<<256, 256, 0, stream>>>(x, n1w1, n1b1, n1w2, n1b2, h1);

    edge_gemm<512, 2, false><<<BE / 256, 512, 163840, stream>>>(
        h1, nullptr, w1e1, e1b1, w2e1, e1b2, e1, nullptr, nullptr, nullptr);

    agg_kernel<<<B_ * N_, 256, 0, stream>>>(e1, aggf);

    node_mlp4<256><<<256, 256, 0, stream>>>(aggf, n2w1, n2b1, n2w2, n2b2, h2);

    edge_gemm<768, 3, true><<<BE / 256, 512, 163840, stream>>>(
        h2, e1, w1e2, e2b1, w2e2, e2b2, nullptr, ow, ob, out);
}

// Round 4
// 225.191 us; speedup vs baseline: 1.2952x; 1.2952x over previous
//
#include <hip/hip_runtime.h>
#include <hip/hip_bf16.h>

typedef unsigned short ushort_t;
typedef short bf16x8 __attribute__((ext_vector_type(8)));
typedef float f32x4 __attribute__((ext_vector_type(4)));

#define B_ 8
#define N_ 128
#define E_ 16256           // 128*127
#define BE 130048          // 8*E_

__device__ __forceinline__ float eluf(float x) {
    return x > 0.0f ? x : __expf(x) - 1.0f;
}
__device__ __forceinline__ ushort_t f2bf(float f) {
    union { float f; unsigned u; } v; v.f = f;
    return (ushort_t)((v.u + 0x7fffu + ((v.u >> 16) & 1u)) >> 16);
}
__device__ __forceinline__ float bf2f(ushort_t h) {
    union { unsigned u; float f; } v; v.u = ((unsigned)h) << 16;
    return v.f;
}

// async global->LDS, 16B per lane; LDS dest = wave-uniform base + lane*16.
__device__ __forceinline__ void glds16(void* lds, const void* g) {
    __builtin_amdgcn_global_load_lds(
        (const __attribute__((address_space(1))) unsigned int*)g,
        (__attribute__((address_space(3))) unsigned int*)lds, 16, 0, 0);
}

// ---------------- weight image builders (fused) ----------------
// img32: chunk c (32k x 256n = 16KB): img[c][n][q'][j] = w[c*32 + (q'^((n>>1)&3))*8 + j][n]
__device__ __forceinline__ void img32_elem(const float* __restrict__ w,
                                           ushort_t* __restrict__ img, int i) {
    int c = i >> 13;  int r = i & 8191;
    int n = r >> 5;   int jq = r & 31;
    int quad = jq >> 3, j = jq & 7;
    int kc = quad ^ ((n >> 1) & 3);
    int k = c * 32 + kc * 8 + j;
    img[i] = f2bf(w[(size_t)k * 256 + n]);
}

__global__ __launch_bounds__(256) void wprep_all(
    const float* __restrict__ w1e1, ushort_t* __restrict__ i1,
    const float* __restrict__ w2e1, ushort_t* __restrict__ i2,
    const float* __restrict__ w1e2, ushort_t* __restrict__ i3,
    const float* __restrict__ w2e2, ushort_t* __restrict__ i4)
{
    int gid = blockIdx.x * 256 + threadIdx.x;
    if (gid < 131072)            img32_elem(w1e1, i1, gid);
    else if (gid < 196608)       img32_elem(w2e1, i2, gid - 131072);
    else if (gid < 393216)       img32_elem(w1e2, i3, gid - 196608);
    else                         img32_elem(w2e2, i4, gid - 393216);
}

// ---------------- node MLP: fp32, 4 rows per block ----------------
template<int K>
__global__ __launch_bounds__(256) void node_mlp4(
    const float* __restrict__ in, const float* __restrict__ w1,
    const float* __restrict__ b1, const float* __restrict__ w2,
    const float* __restrict__ b2, ushort_t* __restrict__ outbf)
{
    __shared__ float xl[4][K];
    __shared__ float hl[4][256];
    const int r0 = blockIdx.x * 4, t = threadIdx.x;
    for (int idx = t; idx < 4 * K; idx += 256) {
        int r = idx / K, k = idx - r * K;
        xl[r][k] = in[(size_t)(r0 + r) * K + k];
    }
    __syncthreads();
    float a[4];
    const float bb1 = b1[t];
    #pragma unroll
    for (int r = 0; r < 4; ++r) a[r] = bb1;
    #pragma unroll 4
    for (int k = 0; k < K; ++k) {
        const float wv = w1[(size_t)k * 256 + t];
        #pragma unroll
        for (int r = 0; r < 4; ++r) a[r] = fmaf(xl[r][k], wv, a[r]);
    }
    #pragma unroll
    for (int r = 0; r < 4; ++r) hl[r][t] = eluf(a[r]);
    __syncthreads();
    const float bb2 = b2[t];
    #pragma unroll
    for (int r = 0; r < 4; ++r) a[r] = bb2;
    #pragma unroll 4
    for (int k = 0; k < 256; ++k) {
        const float wv = w2[(size_t)k * 256 + t];
        #pragma unroll
        for (int r = 0; r < 4; ++r) a[r] = fmaf(hl[r][k], wv, a[r]);
    }
    #pragma unroll
    for (int r = 0; r < 4; ++r)
        outbf[(size_t)(r0 + r) * 256 + t] = f2bf(eluf(a[r]));
}

// ---------------- contiguous segment-sum aggregation ----------------
__global__ __launch_bounds__(256) void agg_kernel(const ushort_t* __restrict__ e1,
                                                  float* __restrict__ agg)
{
    __shared__ float red[8][256];
    const int bn = blockIdx.x;
    const int b = bn >> 7, n = bn & 127;
    const int t = threadIdx.x;
    const int u = t & 31, g = t >> 5;
    const ushort_t* base = e1 + ((size_t)b * E_ + (size_t)n * 127) * 256 + u * 8;
    float s[8] = {0.f,0.f,0.f,0.f,0.f,0.f,0.f,0.f};
    for (int j = g; j < 127; j += 8) {
        bf16x8 v = *(const bf16x8*)(base + (size_t)j * 256);
        #pragma unroll
        for (int c = 0; c < 8; ++c) s[c] += bf2f((ushort_t)v[c]);
    }
    #pragma unroll
    for (int c = 0; c < 8; ++c) red[g][u * 8 + c] = s[c];
    __syncthreads();
    float tot = 0.f;
    #pragma unroll
    for (int gg = 0; gg < 8; ++gg) tot += red[gg][t];
    agg[(size_t)bn * 256 + t] = tot;
}

// ---------------- fused 2-layer edge MLP, 4-wave 128x256 block, 80KB LDS ----------------
// 2 blocks/CU: cross-block overlap hides per-chunk load drains (round-2 schedule kept).
// LDS (81920B dynamic):
//   layer 1: A ring [0, 2x8K)  B ring [16K, 2x16K)   (both inside future Hid)
//   layer 2: Hid [0,64K) (128 rows x 512B, XOR-swizzled)  B2 single buf [64K,80K)
template<int K1, int NSEG, bool FINAL>
__global__ __launch_bounds__(256, 2) void edge_gemm(
    const ushort_t* __restrict__ hnode,     // [B*N][256] bf16
    const ushort_t* __restrict__ skipsrc,   // [BE][256] bf16 (NSEG==3)
    const ushort_t* __restrict__ w1img, const float* __restrict__ b1,
    const ushort_t* __restrict__ w2img, const float* __restrict__ b2,
    ushort_t* __restrict__ eout,
    const float* __restrict__ ow, const float* __restrict__ ob,
    float* __restrict__ out)
{
    extern __shared__ char smem[];
    char* Aring = smem;               // 2 x 8192   (layer 1)
    char* Bring = smem + 16384;       // 2 x 16384  (layer 1)
    char* B2buf = smem + 65536;       // 16384      (layer 2, single buffer)

    const int t    = threadIdx.x;
    const int wid  = t >> 6;          // 0..3
    const int lane = t & 63;
    const int lr   = lane & 15;
    const int lg   = lane >> 4;
    const int wr   = wid >> 1;        // 0..1 (64-row group)
    const int wc   = wid & 1;         // 0..1 (128-col group)
    const int q4   = (lg ^ ((lr >> 1) & 3)) << 4;

    const int blockRow = blockIdx.x * 128;

    // ---- A-staging per-lane constants: it=0,1 units of 1KB per wave ----
    // global unit g = (it*4+wid)*64 + lane; row = g>>2 (0..127); quad = (g&3)^((row>>1)&3)
    const ushort_t* a0[2];
    const ushort_t* a1[2];
    const ushort_t* a2[2];
    #pragma unroll
    for (int it = 0; it < 2; ++it) {
        int g  = (it * 4 + wid) * 64 + lane;
        int rA = g >> 2;
        int kcA = (g & 3) ^ ((rA >> 1) & 3);
        int rg = blockRow + rA;
        int b  = rg / E_;  int e = rg - b * E_;
        int rcv = e / 127; int kk = e - rcv * 127;
        int snd = kk + (kk >= rcv ? 1 : 0);
        a0[it] = hnode + (size_t)(b * N_ + rcv) * 256 + kcA * 8;
        a1[it] = hnode + (size_t)(b * N_ + snd) * 256 + kcA * 8;
        a2[it] = (NSEG == 3) ? skipsrc + (size_t)rg * 256 + kcA * 8 : a0[it];
    }

    float bias1[8], bias2[8];
    #pragma unroll
    for (int f = 0; f < 8; ++f) {
        int col = wc * 128 + f * 16 + lr;
        bias1[f] = b1[col];
        bias2[f] = b2[col];
    }

    f32x4 acc[4][8];
    #pragma unroll
    for (int m = 0; m < 4; ++m)
        #pragma unroll
        for (int f = 0; f < 8; ++f) acc[m][f] = f32x4{0.f, 0.f, 0.f, 0.f};

    // ---- staging helpers (per wave: B=4 glds, A=2 glds, B2=4 glds) ----
    auto stageB = [&](int c, int p) {
        const char* src = (const char*)w1img + (size_t)c * 16384 + wid * 4096 + lane * 16;
        char* dst = Bring + p * 16384 + wid * 4096;
        #pragma unroll
        for (int it = 0; it < 4; ++it) glds16(dst + it * 1024, src + it * 1024);
    };
    auto stageA = [&](int k0, int p) {
        char* dst = Aring + p * 8192 + wid * 1024;
        #pragma unroll
        for (int it = 0; it < 2; ++it) {
            const ushort_t* bp;
            if (NSEG == 3) bp = (k0 < 256) ? a0[it] : (k0 < 512 ? a1[it] : a2[it]);
            else           bp = (k0 < 256) ? a0[it] : a1[it];
            glds16(dst + it * 4096, bp + (k0 & 255));
        }
    };
    auto stageB2 = [&](int c) {
        const char* src = (const char*)w2img + (size_t)c * 16384 + wid * 1024 + lane * 16;
        char* dst = B2buf + wid * 1024;
        #pragma unroll
        for (int it = 0; it < 4; ++it) glds16(dst + it * 4096, src + it * 4096);
    };

    // ================= layer 1: K-chunk 32, dbuf ring, round-2 schedule =================
    constexpr int NC1 = K1 / 32;
    stageB(0, 0);
    stageA(0, 0);
    __syncthreads();
    for (int c = 0; c < NC1; ++c) {
        const int p = c & 1;
        if (c + 1 < NC1) { stageB(c + 1, p ^ 1); stageA((c + 1) * 32, p ^ 1); }
        const char* Ab = Aring + p * 8192;
        const char* Bb = Bring + p * 16384;
        bf16x8 a[4], b[8];
        #pragma unroll
        for (int m = 0; m < 4; ++m)
            a[m] = *(const bf16x8*)(Ab + (wr * 64 + m * 16 + lr) * 64 + q4);
        #pragma unroll
        for (int f = 0; f < 8; ++f)
            b[f] = *(const bf16x8*)(Bb + (wc * 128 + f * 16 + lr) * 64 + q4);
        #pragma unroll
        for (int m = 0; m < 4; ++m)
            #pragma unroll
            for (int f = 0; f < 8; ++f)
                acc[m][f] = __builtin_amdgcn_mfma_f32_16x16x32_bf16(a[m], b[f], acc[m][f], 0, 0, 0);
        __syncthreads();
    }

    // ---- transition: bias+elu -> Hid (bf16, XOR layout) over rings, reset acc ----
    #pragma unroll
    for (int m = 0; m < 4; ++m)
        #pragma unroll
        for (int f = 0; f < 8; ++f) {
            const int col = wc * 128 + f * 16 + lr;
            const int ch = col >> 3;
            #pragma unroll
            for (int r = 0; r < 4; ++r) {
                const int row = wr * 64 + m * 16 + lg * 4 + r;
                float v = eluf(acc[m][f][r] + bias1[f]);
                *(ushort_t*)(smem + row * 512 + ((ch ^ (row & 7)) << 4) + ((col & 7) << 1)) = f2bf(v);
            }
            acc[m][f] = f32x4{0.f, 0.f, 0.f, 0.f};
        }

    // ================= layer 2: K-chunk 32, single-buffered B2 =================
    for (int c = 0; c < 8; ++c) {
        stageB2(c);
        __syncthreads();                 // drains stage + fences Hid writes (c==0)
        bf16x8 a[4], b[8];
        const int qh = ((c * 4 + lg) ^ (lr & 7)) << 4;
        #pragma unroll
        for (int m = 0; m < 4; ++m)
            a[m] = *(const bf16x8*)(smem + (wr * 64 + m * 16 + lr) * 512 + qh);
        #pragma unroll
        for (int f = 0; f < 8; ++f)
            b[f] = *(const bf16x8*)(B2buf + (wc * 128 + f * 16 + lr) * 64 + q4);
        #pragma unroll
        for (int m = 0; m < 4; ++m)
            #pragma unroll
            for (int f = 0; f < 8; ++f)
                acc[m][f] = __builtin_amdgcn_mfma_f32_16x16x32_bf16(a[m], b[f], acc[m][f], 0, 0, 0);
        __syncthreads();                 // protect B2 before next stage
    }

    if (!FINAL) {
        // ---- epilogue: elu+bias -> wave-private LDS slice -> coalesced stores ----
        char* slice = smem + wid * 16384;
        #pragma unroll
        for (int m = 0; m < 4; ++m)
            #pragma unroll
            for (int f = 0; f < 8; ++f) {
                const int col = f * 16 + lr;         // local 0..127
                const int cc = col >> 3;
                #pragma unroll
                for (int r = 0; r < 4; ++r) {
                    const int row = m * 16 + lg * 4 + r;   // local 0..63
                    float v = eluf(acc[m][f][r] + bias2[f]);
                    *(ushort_t*)(slice + row * 256 + ((cc ^ (row & 7)) << 4) + ((col & 7) << 1)) = f2bf(v);
                }
            }
        asm volatile("s_waitcnt lgkmcnt(0)" ::: "memory");
        #pragma unroll
        for (int it = 0; it < 16; ++it) {
            const int q = it * 64 + lane;
            const int row = q >> 4, ccp = q & 15;
            bf16x8 v = *(const bf16x8*)(slice + row * 256 + (ccp << 4));
            const int cc = ccp ^ (row & 7);
            const int grow = blockRow + wr * 64 + row;
            *(bf16x8*)(eout + (size_t)grow * 256 + wc * 128 + cc * 8) = v;
        }
    } else {
        // ---- epilogue: fused projection to [row][2] ----
        float ow0[8], ow1[8];
        #pragma unroll
        for (int f = 0; f < 8; ++f) {
            int col = wc * 128 + f * 16 + lr;
            ow0[f] = ow[col * 2 + 0];
            ow1[f] = ow[col * 2 + 1];
        }
        float s0[4][4], s1[4][4];
        #pragma unroll
        for (int m = 0; m < 4; ++m)
            #pragma unroll
            for (int r = 0; r < 4; ++r) { s0[m][r] = 0.f; s1[m][r] = 0.f; }
        #pragma unroll
        for (int m = 0; m < 4; ++m)
            #pragma unroll
            for (int f = 0; f < 8; ++f)
                #pragma unroll
                for (int r = 0; r < 4; ++r) {
                    float v = eluf(acc[m][f][r] + bias2[f]);
                    s0[m][r] = fmaf(v, ow0[f], s0[m][r]);
                    s1[m][r] = fmaf(v, ow1[f], s1[m][r]);
                }
        #pragma unroll
        for (int msk = 1; msk <= 8; msk <<= 1)
            #pragma unroll
            for (int m = 0; m < 4; ++m)
                #pragma unroll
                for (int r = 0; r < 4; ++r) {
                    s0[m][r] += __shfl_xor(s0[m][r], msk);
                    s1[m][r] += __shfl_xor(s1[m][r], msk);
                }
        float* part = (float*)smem;   // [128 rows][2 ch][2 wc] = 2KB
        if (lr == 0) {
            #pragma unroll
            for (int m = 0; m < 4; ++m)
                #pragma unroll
                for (int r = 0; r < 4; ++r) {
                    const int row = wr * 64 + m * 16 + lg * 4 + r;
                    part[(row * 2 + 0) * 2 + wc] = s0[m][r];
                    part[(row * 2 + 1) * 2 + wc] = s1[m][r];
                }
        }
        __syncthreads();
        if (t < 256) {
            const int row = t >> 1, chn = t & 1;
            float val = part[(row * 2 + chn) * 2 + 0] + part[(row * 2 + chn) * 2 + 1] + ob[chn];
            out[(size_t)(blockRow + row) * 2 + chn] = val;
        }
    }
}

extern "C" void kernel_launch(void* const* d_in, const int* in_sizes, int n_in,
                              void* d_out, int out_size, void* d_ws, size_t ws_size,
                              hipStream_t stream)
{
    const float* x    = (const float*)d_in[0];
    const float* n1w1 = (const float*)d_in[3];
    const float* n1b1 = (const float*)d_in[4];
    const float* n1w2 = (const float*)d_in[5];
    const float* n1b2 = (const float*)d_in[6];
    const float* e1w1 = (const float*)d_in[7];
    const float* e1b1 = (const float*)d_in[8];
    const float* e1w2 = (const float*)d_in[9];
    const float* e1b2 = (const float*)d_in[10];
    const float* n2w1 = (const float*)d_in[11];
    const float* n2b1 = (const float*)d_in[12];
    const float* n2w2 = (const float*)d_in[13];
    const float* n2b2 = (const float*)d_in[14];
    const float* e2w1 = (const float*)d_in[15];
    const float* e2b1 = (const float*)d_in[16];
    const float* e2w2 = (const float*)d_in[17];
    const float* e2b2 = (const float*)d_in[18];
    const float* ow   = (const float*)d_in[19];
    const float* ob   = (const float*)d_in[20];

    char* ws = (char*)d_ws;
    ushort_t* h1   = (ushort_t*)(ws + 0);                      // 512 KB
    ushort_t* h2   = (ushort_t*)(ws + (512u << 10));           // 512 KB
    float*    aggf = (float*)(ws + (1u << 20));                // 1 MB
    ushort_t* e1   = (ushort_t*)(ws + (2u << 20));             // 66.6 MB
    size_t off = (size_t)(2u << 20) + (size_t)BE * 256 * 2;
    ushort_t* w1e1 = (ushort_t*)(ws + off); off += (size_t)512 * 256 * 2;
    ushort_t* w2e1 = (ushort_t*)(ws + off); off += (size_t)256 * 256 * 2;
    ushort_t* w1e2 = (ushort_t*)(ws + off); off += (size_t)768 * 256 * 2;
    ushort_t* w2e2 = (ushort_t*)(ws + off);

    float* out = (float*)d_out;

    hipFuncSetAttribute((const void*)edge_gemm<512, 2, false>,
                        hipFuncAttributeMaxDynamicSharedMemorySize, 81920);
    hipFuncSetAttribute((const void*)edge_gemm<768, 3, true>,
                        hipFuncAttributeMaxDynamicSharedMemorySize, 81920);

    wprep_all<<<1792, 256, 0, stream>>>(e1w1, w1e1, e1w2, w2e1, e2w1, w1e2, e2w2, w2e2);

    node_mlp4<196><<<256, 256, 0, stream>>>(x, n1w1, n1b1, n1w2, n1b2, h1);

    edge_gemm<512, 2, false><<<BE / 128, 256, 81920, stream>>>(
        h1, nullptr, w1e1, e1b1, w2e1, e1b2, e1, nullptr, nullptr, nullptr);

    agg_kernel<<<B_ * N_, 256, 0, stream>>>(e1, aggf);

    node_mlp4<256><<<256, 256, 0, stream>>>(aggf, n2w1, n2b1, n2w2, n2b2, h2);

    edge_gemm<768, 3, true><<<BE / 128, 256, 81920, stream>>>(
        h2, e1, w1e2, e2b1, w2e2, e2b2, nullptr, ow, ob, out);
}